// Round 5
// baseline (3992.376 us; speedup 1.0000x reference)
//
#include <hip/hip_runtime.h>
#include <stdint.h>

// ---------------------------------------------------------------------------
// HMM forward: B=256, T=512, Q=1027, ALPHA=26.
// 16 clusters x 16 WGs (256 thr, 4 waves). Cluster c owns batches [16c,16c+16).
// Wave (j,w) owns 16-col tile tg=4j+w; WG15 also owns cols 1024..1026
// (tile 64, k-split over its 4 waves). Exchange image in MFMA A-fragment
// layout: chunk16B(kc,l) = { g[m=l&15][k=kc*32+(l>>4)*8+e] : e=0..7 }.
// KEY CHANGE (R5): no S exchange. Consumers compute S[m] = sum_k g[m][k]
// directly from the staged bf16 image (identical bytes + identical reduction
// order in every WG -> bitwise-consistent S across the cluster).
// POST: 4 g-stores -> counted vmcnt drain (out-stores excluded) -> wave flag.
// All cross-WG traffic uses sc0 sc1 (device-coherent, placement-independent).
// ---------------------------------------------------------------------------

#define Q     1027
#define TT    512
#define ALPH  26
#define KCH   33              // k-chunks of 32 (K padded to 1056)
#define NTILE 65
#define NCHK  (KCH*64)        // 2112 chunks
#define GIMG  (NCHK*16)       // 33792 B per (cluster,parity) image
#define NCL   16
#define WPC   16
#define NWG   (NCL*WPC)       // 256
#define MB    16              // batches per cluster

typedef short  short8  __attribute__((ext_vector_type(8)));
typedef float  floatx4 __attribute__((ext_vector_type(4)));
typedef int    intx4   __attribute__((ext_vector_type(4)));

static constexpr size_t al512(size_t x) { return (x + 511) & ~size_t(511); }
static constexpr size_t OFF_APACK = 0;
static constexpr size_t SZ_APACK  = (size_t)NTILE * KCH * 64 * 16;   // 2,196,480
static constexpr size_t OFF_BSOFT = al512(OFF_APACK + SZ_APACK);
static constexpr size_t SZ_BSOFT  = (size_t)Q * ALPH * 4;
static constexpr size_t OFF_INIT  = al512(OFF_BSOFT + SZ_BSOFT);
static constexpr size_t OFF_AMAX  = al512(OFF_INIT + Q * 4);
static constexpr size_t OFF_AINV  = al512(OFF_AMAX + Q * 4);
static constexpr size_t OFF_GEX   = al512(OFF_AINV + Q * 4);
static constexpr size_t SZ_GEX    = (size_t)NCL * 2 * GIMG;          // 1,081,344
static constexpr size_t OFF_FLAGS = al512(OFF_GEX + SZ_GEX);         // [c][tg 64] int
static constexpr size_t SZ_FLAGS  = (size_t)NCL * 64 * 4;            // 4,096
static constexpr size_t WS_NEED   = OFF_FLAGS + SZ_FLAGS;            // ~3.3 MB
static constexpr size_t FWDSZ     = (size_t)256 * TT * Q;

__device__ __forceinline__ uint32_t f2bf(float f) {
  uint32_t u = __float_as_uint(f);
  return (u + 0x7fffu + ((u >> 16) & 1u)) >> 16;   // RNE
}

__device__ __forceinline__ float sum8(intx4 v) {
  float s = 0.f;
#pragma unroll
  for (int e = 0; e < 4; ++e) {
    const uint32_t u = (uint32_t)v[e];
    s += __uint_as_float(u << 16);
    s += __uint_as_float(u & 0xffff0000u);
  }
  return s;
}

// ------------------------- prep kernels ------------------------------------

__global__ void k_zero(char* __restrict__ ws) {
  const size_t n = (OFF_FLAGS + SZ_FLAGS - OFF_GEX) / 16;
  intx4* p = (intx4*)(ws + OFF_GEX);
  for (size_t i = (size_t)blockIdx.x * 256 + threadIdx.x; i < n; i += (size_t)64 * 256)
    p[i] = intx4{0, 0, 0, 0};
}

__global__ void k_astats(const float* __restrict__ A, char* __restrict__ ws) {
  const int r = blockIdx.x, tid = threadIdx.x;
  const float* row = A + (size_t)r * Q;
  __shared__ float red[4], red2[4];
  float mx = -3.0e38f;
  for (int i = tid; i < Q; i += 256) mx = fmaxf(mx, row[i]);
#pragma unroll
  for (int d = 1; d < 64; d <<= 1) mx = fmaxf(mx, __shfl_xor(mx, d));
  if ((tid & 63) == 0) red[tid >> 6] = mx;
  __syncthreads();
  mx = fmaxf(fmaxf(red[0], red[1]), fmaxf(red[2], red[3]));
  float s = 0.f;
  for (int i = tid; i < Q; i += 256) s += expf(row[i] - mx);
#pragma unroll
  for (int d = 1; d < 64; d <<= 1) s += __shfl_xor(s, d);
  if ((tid & 63) == 0) red2[tid >> 6] = s;
  __syncthreads();
  s = red2[0] + red2[1] + red2[2] + red2[3];
  if (tid == 0) {
    *(float*)(ws + OFF_AMAX + (size_t)r * 4) = mx;
    *(float*)(ws + OFF_AINV + (size_t)r * 4) = 1.0f / s;
  }
}

__global__ void k_bsoft(const float* __restrict__ Bl, char* __restrict__ ws) {
  const int r = blockIdx.x, l = threadIdx.x;  // 64 threads
  float v = (l < ALPH) ? Bl[(size_t)r * ALPH + l] : -3.0e38f;
  float mx = v;
#pragma unroll
  for (int d = 1; d < 64; d <<= 1) mx = fmaxf(mx, __shfl_xor(mx, d));
  float e = (l < ALPH) ? expf(v - mx) : 0.f;
  float s = e;
#pragma unroll
  for (int d = 1; d < 64; d <<= 1) s += __shfl_xor(s, d);
  if (l < ALPH) *(float*)(ws + OFF_BSOFT + ((size_t)r * ALPH + l) * 4) = e / s;
}

__global__ void k_isoft(const float* __restrict__ il, char* __restrict__ ws) {
  const int tid = threadIdx.x;
  __shared__ float red[4], red2[4];
  float mx = -3.0e38f;
  for (int i = tid; i < Q; i += 256) mx = fmaxf(mx, il[i]);
#pragma unroll
  for (int d = 1; d < 64; d <<= 1) mx = fmaxf(mx, __shfl_xor(mx, d));
  if ((tid & 63) == 0) red[tid >> 6] = mx;
  __syncthreads();
  mx = fmaxf(fmaxf(red[0], red[1]), fmaxf(red[2], red[3]));
  float s = 0.f;
  for (int i = tid; i < Q; i += 256) s += expf(il[i] - mx);
#pragma unroll
  for (int d = 1; d < 64; d <<= 1) s += __shfl_xor(s, d);
  if ((tid & 63) == 0) red2[tid >> 6] = s;
  __syncthreads();
  s = red2[0] + red2[1] + red2[2] + red2[3];
  const float inv = 1.0f / s;
  for (int i = tid; i < Q; i += 256)
    *(float*)(ws + OFF_INIT + (size_t)i * 4) = expf(il[i] - mx) * inv;
}

// Apack[ntile][kc][lane][e] = A[k = kc*32 + (lane>>4)*8 + e][q = ntile*16 + (lane&15)]
__global__ void k_repack(const float* __restrict__ A, char* __restrict__ ws) {
  const int b = blockIdx.x;
  const int nt = b % NTILE, kc = b / NTILE;
  const int lane = threadIdx.x;
  const int q = nt * 16 + (lane & 15);
  const int kb = kc * 32 + (lane >> 4) * 8;
  union { short8 v; unsigned short u[8]; } pk;
#pragma unroll
  for (int e = 0; e < 8; ++e) {
    const int k = kb + e;
    float val = 0.f;
    if (k < Q && q < Q) {
      const float mxk = *(const float*)(ws + OFF_AMAX + (size_t)k * 4);
      const float ivk = *(const float*)(ws + OFF_AINV + (size_t)k * 4);
      val = expf(A[(size_t)k * Q + q] - mxk) * ivk;
    }
    pk.u[e] = (unsigned short)f2bf(val);
  }
  *(short8*)(ws + OFF_APACK + (((size_t)nt * KCH + kc) * 64 + lane) * 16) = pk.v;
}

// ------------------------- main persistent kernel --------------------------

__global__ __launch_bounds__(256, 1) void k_main(const int* __restrict__ xin,
                                                 char* __restrict__ ws,
                                                 float* __restrict__ out) {
  const int bid = blockIdx.x;            // 256 WGs
  const int c = bid & 15, j = bid >> 4;  // cluster 0..15, WG 0..15
  const int tid = threadIdx.x;
  const int lane = tid & 63, w = tid >> 6;
  const int cL = lane & 15, g4 = lane >> 4;
  const int tg = 4 * j + w;              // 16-col tile 0..63
  const bool jx = (j == 15);
  const bool own64 = (jx && w == 3);
  const uint64_t wsu = (uint64_t)(uintptr_t)ws;
  const uint64_t outu = (uint64_t)(uintptr_t)out;

  __shared__ intx4   g_lds[NCHK];        // 33792 B, fragment order
  __shared__ float   B_lds[5][16][ALPH]; // 8320
  __shared__ uint8_t x_lds[MB * TT];     // 8192
  __shared__ floatx4 accx[4][64];        // 4096 (tile64 partials, WG15)
  __shared__ float   init_lds[5][16];    // 320
  __shared__ float   SpP[4][16];         // per-wave batch sums

  // ---- stage per-WG constants ----
  for (int idx = tid; idx < MB * TT; idx += 256)
    x_lds[idx] = (uint8_t)xin[(size_t)(c * MB) * TT + idx];
  for (int idx = tid; idx < 5 * 16 * ALPH; idx += 256) {
    const int tl = idx / (16 * ALPH), rem = idx % (16 * ALPH);
    const int cc = rem / ALPH, a = rem % ALPH;
    const int grow = (tl < 4 ? 16 * (4 * j + tl) : 1024) + cc;
    B_lds[tl][cc][a] = (grow < Q) ? *(const float*)(ws + OFF_BSOFT + ((size_t)grow * ALPH + a) * 4) : 0.f;
  }
  for (int idx = tid; idx < 5 * 16; idx += 256) {
    const int tl = idx >> 4, cc = idx & 15;
    const int grow = (tl < 4 ? 16 * (4 * j + tl) : 1024) + cc;
    init_lds[tl][cc] = (grow < Q) ? *(const float*)(ws + OFF_INIT + (size_t)grow * 4) : 0.f;
  }

  // ---- persistent A fragments ----
  short8 af0[KCH];
#pragma unroll
  for (int kc = 0; kc < KCH; ++kc)
    af0[kc] = *(const short8*)(ws + OFF_APACK + (((size_t)tg * KCH + kc) * 64 + lane) * 16);
  short8 afx[9];
  if (jx) {
#pragma unroll
    for (int i = 0; i < 9; ++i) {
      if (i < 8 || w == 3) {
        const int kc = 8 * w + i;   // w3 also gets kc=32
        afx[i] = *(const short8*)(ws + OFF_APACK + (((size_t)64 * KCH + kc) * 64 + lane) * 16);
      }
    }
  }
  __syncthreads();

  float up[4], upx[4] = {0, 0, 0, 0};
  float uold[4], uxold[4] = {0, 0, 0, 0}, invS[4];
  float llacc = 0.f;

  // publish step TCUR: 4 g-stores (+4 for own64), out-stores for OT after,
  // counted drain so g (not out) is flushed, then per-wave flag.
#define POSTSTEP(TCUR, OT, HASOUT)                                                        \
  do {                                                                                    \
    const int par_ = (TCUR) & 1;                                                          \
    const uint64_t gb_ = wsu + OFF_GEX + (size_t)(c * 2 + par_) * GIMG;                   \
    const uint64_t b0_ = gb_ + (size_t)((tg >> 1) * 1024 + ((tg & 1) * 2 + (cL >> 3)) * 256 \
                         + g4 * 64 + (cL & 7) * 2);                                       \
    _Pragma("unroll") for (int r_ = 0; r_ < 4; ++r_) {                                    \
      uint32_t v_ = f2bf(up[r_]);                                                         \
      asm volatile("global_store_short %0, %1, off sc0 sc1" ::                            \
                   "v"(b0_ + (size_t)(r_ * 16)), "v"(v_) : "memory");                     \
    }                                                                                     \
    if (own64) {                                                                          \
      const uint64_t bx_ = gb_ + (size_t)(32 * 1024 + (cL >> 3) * 256 + g4 * 64 + (cL & 7) * 2); \
      _Pragma("unroll") for (int r_ = 0; r_ < 4; ++r_) {                                  \
        uint32_t v_ = f2bf(upx[r_]);                                                      \
        asm volatile("global_store_short %0, %1, off sc0 sc1" ::                          \
                     "v"(bx_ + (size_t)(r_ * 16)), "v"(v_) : "memory");                   \
      }                                                                                   \
    }                                                                                     \
    if (HASOUT) {                                                                         \
      _Pragma("unroll") for (int r_ = 0; r_ < 4; ++r_) {                                  \
        const int m_ = g4 * 4 + r_;                                                       \
        const uint64_t oa_ = outu + (((size_t)(c * MB + m_) * TT + (OT)) * Q + tg * 16 + cL) * 4; \
        const float ov_ = uold[r_] * invS[r_];                                            \
        asm volatile("global_store_dword %0, %1, off nt" :: "v"(oa_), "v"(ov_) : "memory"); \
      }                                                                                   \
      if (own64 && cL < 3) {                                                              \
        _Pragma("unroll") for (int r_ = 0; r_ < 4; ++r_) {                                \
          const int m_ = g4 * 4 + r_;                                                     \
          const uint64_t oa_ = outu + (((size_t)(c * MB + m_) * TT + (OT)) * Q + 1024 + cL) * 4; \
          const float ov_ = uxold[r_] * invS[r_];                                         \
          asm volatile("global_store_dword %0, %1, off nt" :: "v"(oa_), "v"(ov_) : "memory"); \
        }                                                                                 \
      }                                                                                   \
      if (own64) { asm volatile("s_waitcnt vmcnt(8)" ::: "memory"); }                     \
      else       { asm volatile("s_waitcnt vmcnt(4)" ::: "memory"); }                     \
    } else {                                                                              \
      asm volatile("s_waitcnt vmcnt(0)" ::: "memory");                                    \
    }                                                                                     \
    __builtin_amdgcn_sched_barrier(0);                                                    \
    if (lane == 0) {                                                                      \
      int fv_ = (TCUR) + 1;                                                               \
      asm volatile("global_store_dword %0, %1, off sc0 sc1" ::                            \
                   "v"(wsu + OFF_FLAGS + (size_t)(c * 64 + tg) * 4), "v"(fv_) : "memory");\
    }                                                                                     \
  } while (0)

  // ---- step 0: u0 = E0 * init ----
#pragma unroll
  for (int r = 0; r < 4; ++r) {
    const int m = g4 * 4 + r;
    const int xm = x_lds[m * TT + 0];
    up[r] = B_lds[w][cL][xm] * init_lds[w][cL];
    if (own64) upx[r] = B_lds[4][cL][xm] * init_lds[4][cL];
  }
  POSTSTEP(0, 0, 0);

  for (int t = 1; t < TT; ++t) {
    const int parp = (t - 1) & 1;

    // wave 0 polls all 64 wave-flags; others wait at B1
    if (w == 0) {
      const uint64_t fa = wsu + OFF_FLAGS + (size_t)(c * 64 + lane) * 4;
      for (;;) {
        int f;
        asm volatile("global_load_dword %0, %1, off sc0 sc1\n\ts_waitcnt vmcnt(0)"
                     : "=v"(f) : "v"(fa) : "memory");
        if (__all(f >= t)) break;
        __builtin_amdgcn_s_sleep(1);
      }
    }
    __syncthreads();  // B1: flags seen

    // stage g_{t-1} (all 256 threads) and accumulate per-batch sums
    const uint64_t gb = wsu + OFF_GEX + (size_t)(c * 2 + parp) * GIMG;
    intx4 sg[8], tl4;
#pragma unroll
    for (int i = 0; i < 8; ++i)
      asm volatile("global_load_dwordx4 %0, %1, off sc0 sc1"
                   : "=v"(sg[i]) : "v"(gb + (size_t)(i * 256 + tid) * 16) : "memory");
    const bool t64 = (tid < 64);
    if (t64)
      asm volatile("global_load_dwordx4 %0, %1, off sc0 sc1"
                   : "=v"(tl4) : "v"(gb + (size_t)(2048 + tid) * 16) : "memory");
    asm volatile("s_waitcnt vmcnt(0)" ::: "memory");
    __builtin_amdgcn_sched_barrier(0);
    float ps = 0.f;
#pragma unroll
    for (int i = 0; i < 8; ++i) { g_lds[i * 256 + tid] = sg[i]; ps += sum8(sg[i]); }
    if (t64) { g_lds[2048 + tid] = tl4; ps += sum8(tl4); }
    // thread's chunks all belong to batch m = tid&15; reduce over lane bits 4,5
    ps += __shfl_xor(ps, 16);
    ps += __shfl_xor(ps, 32);
    if (lane < 16) SpP[w][lane] = ps;
    __syncthreads();  // B2: g_lds + SpP ready

    float llS = 1.f;
#pragma unroll
    for (int r = 0; r < 4; ++r) {
      const int m = g4 * 4 + r;
      invS[r] = 1.0f / (SpP[0][m] + SpP[1][m] + SpP[2][m] + SpP[3][m]);
      uold[r] = up[r];
      if (own64) uxold[r] = upx[r];
    }
    if (lane < 16) llS = SpP[0][lane] + SpP[1][lane] + SpP[2][lane] + SpP[3][lane];

    // matvec: r = g_{t-1} @ A
    floatx4 a0v = {0, 0, 0, 0}, a1v = {0, 0, 0, 0};
#pragma unroll
    for (int kc = 0; kc < KCH; ++kc) {
      const short8 gf = *(const short8*)&g_lds[kc * 64 + lane];
      if (kc & 1) a1v = __builtin_amdgcn_mfma_f32_16x16x32_bf16(gf, af0[kc], a1v, 0, 0, 0);
      else        a0v = __builtin_amdgcn_mfma_f32_16x16x32_bf16(gf, af0[kc], a0v, 0, 0, 0);
    }
    float rx[4];
    if (jx) {  // tile64: k-split over WG15's 4 waves
      floatx4 ax = {0, 0, 0, 0};
#pragma unroll
      for (int i = 0; i < 9; ++i) {
        if (i < 8 || w == 3) {
          const int kc = 8 * w + i;
          const short8 gf = *(const short8*)&g_lds[kc * 64 + lane];
          ax = __builtin_amdgcn_mfma_f32_16x16x32_bf16(gf, afx[i], ax, 0, 0, 0);
        }
      }
      accx[w][lane] = ax;
      __syncthreads();  // WG15-uniform
      if (own64) {
#pragma unroll
        for (int r = 0; r < 4; ++r)
          rx[r] = accx[0][lane][r] + accx[1][lane][r] + accx[2][lane][r] + accx[3][lane][r];
      }
    }

    // epilogue: u~_t = E_t * (g@A) * invS
#pragma unroll
    for (int r = 0; r < 4; ++r) {
      const int m = g4 * 4 + r;
      const int xm = x_lds[m * TT + t];
      up[r] = (a0v[r] + a1v[r]) * B_lds[w][cL][xm] * invS[r];
      if (own64) upx[r] = rx[r] * B_lds[4][cL][xm] * invS[r];
    }
    POSTSTEP(t, t - 1, 1);
    if (j == 0 && w == 0 && lane < 16) llacc += logf(llS);  // off the flag path
  }

  // ---- final: S_511 (from staged sums only), fwd_511, loglik ----
  if (w == 0) {
    const uint64_t fa = wsu + OFF_FLAGS + (size_t)(c * 64 + lane) * 4;
    for (;;) {
      int f;
      asm volatile("global_load_dword %0, %1, off sc0 sc1\n\ts_waitcnt vmcnt(0)"
                   : "=v"(f) : "v"(fa) : "memory");
      if (__all(f >= TT)) break;
      __builtin_amdgcn_s_sleep(1);
    }
  }
  __syncthreads();
  {
    const int parp = (TT - 1) & 1;
    const uint64_t gb = wsu + OFF_GEX + (size_t)(c * 2 + parp) * GIMG;
    intx4 sg[8], tl4;
#pragma unroll
    for (int i = 0; i < 8; ++i)
      asm volatile("global_load_dwordx4 %0, %1, off sc0 sc1"
                   : "=v"(sg[i]) : "v"(gb + (size_t)(i * 256 + tid) * 16) : "memory");
    const bool t64 = (tid < 64);
    if (t64)
      asm volatile("global_load_dwordx4 %0, %1, off sc0 sc1"
                   : "=v"(tl4) : "v"(gb + (size_t)(2048 + tid) * 16) : "memory");
    asm volatile("s_waitcnt vmcnt(0)" ::: "memory");
    __builtin_amdgcn_sched_barrier(0);
    float ps = 0.f;
#pragma unroll
    for (int i = 0; i < 8; ++i) ps += sum8(sg[i]);
    if (t64) ps += sum8(tl4);
    ps += __shfl_xor(ps, 16);
    ps += __shfl_xor(ps, 32);
    if (lane < 16) SpP[w][lane] = ps;
    __syncthreads();
    float llS = 1.f;
#pragma unroll
    for (int r = 0; r < 4; ++r) {
      const int m = g4 * 4 + r;
      invS[r] = 1.0f / (SpP[0][m] + SpP[1][m] + SpP[2][m] + SpP[3][m]);
    }
    if (lane < 16) llS = SpP[0][lane] + SpP[1][lane] + SpP[2][lane] + SpP[3][lane];
#pragma unroll
    for (int r = 0; r < 4; ++r) {
      const int m = g4 * 4 + r;
      const size_t ob = ((size_t)(c * MB + m) * TT + (TT - 1)) * Q;
      __builtin_nontemporal_store(up[r] * invS[r], out + ob + tg * 16 + cL);
      if (own64 && cL < 3)
        __builtin_nontemporal_store(upx[r] * invS[r], out + ob + 1024 + cL);
    }
    if (j == 0 && w == 0 && lane < 16) {
      llacc += logf(llS);
      out[FWDSZ + (size_t)c * MB + lane] = llacc;
    }
  }
}

// ------------------------- launch ------------------------------------------

extern "C" void kernel_launch(void* const* d_in, const int* in_sizes, int n_in,
                              void* d_out, int out_size, void* d_ws, size_t ws_size,
                              hipStream_t stream) {
  const int*   x    = (const int*)d_in[0];
  const float* Alog = (const float*)d_in[1];
  const float* Blog = (const float*)d_in[2];
  const float* ilog = (const float*)d_in[3];
  char*  ws  = (char*)d_ws;
  float* out = (float*)d_out;
  if (ws_size < WS_NEED) return;  // need ~3.3 MB scratch

  hipLaunchKernelGGL(k_zero,   dim3(64),          dim3(256), 0, stream, ws);
  hipLaunchKernelGGL(k_astats, dim3(Q),           dim3(256), 0, stream, Alog, ws);
  hipLaunchKernelGGL(k_bsoft,  dim3(Q),           dim3(64),  0, stream, Blog, ws);
  hipLaunchKernelGGL(k_isoft,  dim3(1),           dim3(256), 0, stream, ilog, ws);
  hipLaunchKernelGGL(k_repack, dim3(NTILE * KCH), dim3(64),  0, stream, Alog, ws);
  hipLaunchKernelGGL(k_main,   dim3(NWG),         dim3(256), 0, stream, x, ws, out);
}

// Round 6
// 2257.980 us; speedup vs baseline: 1.7681x; 1.7681x over previous
//
#include <hip/hip_runtime.h>
#include <stdint.h>

// ---------------------------------------------------------------------------
// HMM forward: B=256, T=512, Q=1027, ALPHA=26.
// R6 = R1 protocol (best measured: 2418us) + fragment-layout exchange (R3/R5
// verified: bank conflicts 7.6e7 -> ~4e6).
// 16 clusters x 16 WGs (256 thr, 4 waves). Cluster c owns batches [16c,16c+16).
// Wave (j,w) owns 16-col tile tg=4j+w; WG15 also owns cols 1024..1026
// (tile 64, k-split over its 4 waves). Exchange image in MFMA A-fragment
// layout: chunk16B(kc,l) = { g[m=l&15][k=kc*32+(l>>4)*8+e] : e=0..7 },
// 2112 chunks -> staging + LDS + ds_read_b128 all linear, conflict-free.
// Protocol per step (R1 shape, unchanged): g-stores -> in-wave reduce ->
// vmcnt(0) -> syncthreads -> w0: Sp store + vmcnt(0) -> WG flag. Consumer:
// w0 polls 16 WG flags (sleep backoff) -> syncthreads -> stage g + Sp ->
// vmcnt(0) -> LDS -> syncthreads -> MFMA -> epilogue -> POST.
// All cross-WG traffic sc0 sc1 (device scope, placement-independent).
// ---------------------------------------------------------------------------

#define Q     1027
#define TT    512
#define ALPH  26
#define KCH   33              // k-chunks of 32 (K padded to 1056)
#define NTILE 65
#define NCHK  (KCH*64)        // 2112 chunks
#define GIMG  (NCHK*16)       // 33792 B per (cluster,parity) image
#define NCL   16
#define WPC   16
#define MB    16

typedef short  short8  __attribute__((ext_vector_type(8)));
typedef float  floatx4 __attribute__((ext_vector_type(4)));
typedef int    intx4   __attribute__((ext_vector_type(4)));

static constexpr size_t al512(size_t x) { return (x + 511) & ~size_t(511); }
static constexpr size_t OFF_APACK = 0;
static constexpr size_t SZ_APACK  = (size_t)NTILE * KCH * 64 * 16;   // 2,196,480
static constexpr size_t OFF_BSOFT = al512(OFF_APACK + SZ_APACK);
static constexpr size_t SZ_BSOFT  = (size_t)Q * ALPH * 4;
static constexpr size_t OFF_INIT  = al512(OFF_BSOFT + SZ_BSOFT);
static constexpr size_t OFF_AMAX  = al512(OFF_INIT + Q * 4);
static constexpr size_t OFF_AINV  = al512(OFF_AMAX + Q * 4);
static constexpr size_t OFF_GEX   = al512(OFF_AINV + Q * 4);
static constexpr size_t SZ_GEX    = (size_t)NCL * 2 * GIMG;          // 1,081,344
static constexpr size_t OFF_FLAGS = al512(OFF_GEX + SZ_GEX);         // [c][j 16] int
static constexpr size_t SZ_FLAGS  = (size_t)NCL * WPC * 4;
static constexpr size_t OFF_SPART = al512(OFF_FLAGS + SZ_FLAGS);     // [c][p][j 16][m 16] f32
static constexpr size_t SZ_SPART  = (size_t)NCL * 2 * WPC * MB * 4;
static constexpr size_t WS_NEED   = OFF_SPART + SZ_SPART;
static constexpr size_t FWDSZ     = (size_t)256 * TT * Q;

__device__ __forceinline__ uint32_t f2bf(float f) {
  uint32_t u = __float_as_uint(f);
  return (u + 0x7fffu + ((u >> 16) & 1u)) >> 16;   // RNE
}

// ------------------------- prep kernels ------------------------------------

__global__ void k_zero(char* __restrict__ ws) {
  const size_t n = (WS_NEED - OFF_GEX) / 16;
  intx4* p = (intx4*)(ws + OFF_GEX);
  for (size_t i = (size_t)blockIdx.x * 256 + threadIdx.x; i < n; i += (size_t)72 * 256)
    p[i] = intx4{0, 0, 0, 0};
}

__global__ void k_astats(const float* __restrict__ A, char* __restrict__ ws) {
  const int r = blockIdx.x, tid = threadIdx.x;
  const float* row = A + (size_t)r * Q;
  __shared__ float red[4], red2[4];
  float mx = -3.0e38f;
  for (int i = tid; i < Q; i += 256) mx = fmaxf(mx, row[i]);
#pragma unroll
  for (int d = 1; d < 64; d <<= 1) mx = fmaxf(mx, __shfl_xor(mx, d));
  if ((tid & 63) == 0) red[tid >> 6] = mx;
  __syncthreads();
  mx = fmaxf(fmaxf(red[0], red[1]), fmaxf(red[2], red[3]));
  float s = 0.f;
  for (int i = tid; i < Q; i += 256) s += expf(row[i] - mx);
#pragma unroll
  for (int d = 1; d < 64; d <<= 1) s += __shfl_xor(s, d);
  if ((tid & 63) == 0) red2[tid >> 6] = s;
  __syncthreads();
  s = red2[0] + red2[1] + red2[2] + red2[3];
  if (tid == 0) {
    *(float*)(ws + OFF_AMAX + (size_t)r * 4) = mx;
    *(float*)(ws + OFF_AINV + (size_t)r * 4) = 1.0f / s;
  }
}

__global__ void k_bsoft(const float* __restrict__ Bl, char* __restrict__ ws) {
  const int r = blockIdx.x, l = threadIdx.x;  // 64 threads
  float v = (l < ALPH) ? Bl[(size_t)r * ALPH + l] : -3.0e38f;
  float mx = v;
#pragma unroll
  for (int d = 1; d < 64; d <<= 1) mx = fmaxf(mx, __shfl_xor(mx, d));
  float e = (l < ALPH) ? expf(v - mx) : 0.f;
  float s = e;
#pragma unroll
  for (int d = 1; d < 64; d <<= 1) s += __shfl_xor(s, d);
  if (l < ALPH) *(float*)(ws + OFF_BSOFT + ((size_t)r * ALPH + l) * 4) = e / s;
}

__global__ void k_isoft(const float* __restrict__ il, char* __restrict__ ws) {
  const int tid = threadIdx.x;
  __shared__ float red[4], red2[4];
  float mx = -3.0e38f;
  for (int i = tid; i < Q; i += 256) mx = fmaxf(mx, il[i]);
#pragma unroll
  for (int d = 1; d < 64; d <<= 1) mx = fmaxf(mx, __shfl_xor(mx, d));
  if ((tid & 63) == 0) red[tid >> 6] = mx;
  __syncthreads();
  mx = fmaxf(fmaxf(red[0], red[1]), fmaxf(red[2], red[3]));
  float s = 0.f;
  for (int i = tid; i < Q; i += 256) s += expf(il[i] - mx);
#pragma unroll
  for (int d = 1; d < 64; d <<= 1) s += __shfl_xor(s, d);
  if ((tid & 63) == 0) red2[tid >> 6] = s;
  __syncthreads();
  s = red2[0] + red2[1] + red2[2] + red2[3];
  const float inv = 1.0f / s;
  for (int i = tid; i < Q; i += 256)
    *(float*)(ws + OFF_INIT + (size_t)i * 4) = expf(il[i] - mx) * inv;
}

// Apack[ntile][kc][lane][e] = A[k = kc*32 + (lane>>4)*8 + e][q = ntile*16 + (lane&15)]
__global__ void k_repack(const float* __restrict__ A, char* __restrict__ ws) {
  const int b = blockIdx.x;
  const int nt = b % NTILE, kc = b / NTILE;
  const int lane = threadIdx.x;
  const int q = nt * 16 + (lane & 15);
  const int kb = kc * 32 + (lane >> 4) * 8;
  union { short8 v; unsigned short u[8]; } pk;
#pragma unroll
  for (int e = 0; e < 8; ++e) {
    const int k = kb + e;
    float val = 0.f;
    if (k < Q && q < Q) {
      const float mxk = *(const float*)(ws + OFF_AMAX + (size_t)k * 4);
      const float ivk = *(const float*)(ws + OFF_AINV + (size_t)k * 4);
      val = expf(A[(size_t)k * Q + q] - mxk) * ivk;
    }
    pk.u[e] = (unsigned short)f2bf(val);
  }
  *(short8*)(ws + OFF_APACK + (((size_t)nt * KCH + kc) * 64 + lane) * 16) = pk.v;
}

// ------------------------- main persistent kernel --------------------------

__global__ __launch_bounds__(256) void k_main(const int* __restrict__ xin,
                                              char* __restrict__ ws,
                                              float* __restrict__ out) {
  const int bid = blockIdx.x;
  const int c = bid & 15, j = bid >> 4;
  const int tid = threadIdx.x;
  const int lane = tid & 63, w = tid >> 6;
  const int cL = lane & 15, g4 = lane >> 4;
  const bool jx = (j == 15), two = (jx && w == 3);
  const int tg = 4 * j + w;            // 16-col tile 0..63
  const uint64_t wsu = (uint64_t)(uintptr_t)ws;

  __shared__ intx4   g_lds[NCHK];        // 33792 B, fragment order
  __shared__ uint8_t x_lds[MB * TT];     // 8192
  __shared__ float   B_lds[5][16][ALPH]; // 8320
  __shared__ float   init_lds[5][16];    // 320
  __shared__ float   Sp_lds[4][16];      // 256
  __shared__ float   accx_lds[4][64][4]; // 4096

  // ---- stage per-WG constants ----
  for (int idx = tid; idx < MB * TT; idx += 256)
    x_lds[idx] = (uint8_t)xin[(size_t)(c * MB) * TT + idx];
  for (int idx = tid; idx < 5 * 16 * ALPH; idx += 256) {
    const int tl = idx / (16 * ALPH), rem = idx % (16 * ALPH);
    const int cc = rem / ALPH, a = rem % ALPH;
    const int grow = (tl < 4 ? 64 * j + tl * 16 : 1024) + cc;
    B_lds[tl][cc][a] = (grow < Q) ? *(const float*)(ws + OFF_BSOFT + ((size_t)grow * ALPH + a) * 4) : 0.f;
  }
  for (int idx = tid; idx < 5 * 16; idx += 256) {
    const int tl = idx / 16, cc = idx % 16;
    const int grow = (tl < 4 ? 64 * j + tl * 16 : 1024) + cc;
    init_lds[tl][cc] = (grow < Q) ? *(const float*)(ws + OFF_INIT + (size_t)grow * 4) : 0.f;
  }

  // ---- persistent A fragments (registers) ----
  short8 af0[KCH];
#pragma unroll
  for (int kc = 0; kc < KCH; ++kc)
    af0[kc] = *(const short8*)(ws + OFF_APACK + (((size_t)tg * KCH + kc) * 64 + lane) * 16);
  short8 af64[9];
  if (jx) {
#pragma unroll
    for (int i = 0; i < 9; ++i) {
      if (i < 8 || w == 3) {
        const int kc = w * 8 + i;
        af64[i] = *(const short8*)(ws + OFF_APACK + (((size_t)64 * KCH + kc) * 64 + lane) * 16);
      }
    }
  }
  __syncthreads();

  float up0[4], up1[4] = {0.f, 0.f, 0.f, 0.f};

  // publish step tcur: fragment-layout g stores + per-WG S partials + flag
#define POST_STEP(TCUR)                                                                   \
  do {                                                                                    \
    const int par_ = (TCUR) & 1;                                                          \
    const uint64_t gb_ = wsu + OFF_GEX + (size_t)(c * 2 + par_) * GIMG;                   \
    const uint64_t b0_ = gb_ + (size_t)((tg >> 1) * 1024 + ((tg & 1) * 2 + (cL >> 3)) * 256 \
                         + g4 * 64 + (cL & 7) * 2);                                       \
    float tmp_[4];                                                                        \
    _Pragma("unroll") for (int r = 0; r < 4; ++r) {                                       \
      uint32_t v0_ = f2bf(up0[r]);                                                        \
      asm volatile("global_store_short %0, %1, off sc0 sc1" ::                            \
                   "v"(b0_ + (size_t)(r * 16)), "v"(v0_) : "memory");                     \
      tmp_[r] = up0[r];                                                                   \
      if (two) {                                                                          \
        const uint64_t bx_ = gb_ + (size_t)(32 * 1024 + (cL >> 3) * 256 + g4 * 64 +       \
                             (cL & 7) * 2);                                               \
        uint32_t v1_ = f2bf(up1[r]);                                                      \
        asm volatile("global_store_short %0, %1, off sc0 sc1" ::                          \
                     "v"(bx_ + (size_t)(r * 16)), "v"(v1_) : "memory");                   \
        tmp_[r] += up1[r];                                                                \
      }                                                                                   \
    }                                                                                     \
    _Pragma("unroll") for (int r = 0; r < 4; ++r) {                                       \
      _Pragma("unroll") for (int d = 1; d < 16; d <<= 1) tmp_[r] += __shfl_xor(tmp_[r], d); \
    }                                                                                     \
    if (cL == 0) {                                                                        \
      _Pragma("unroll") for (int r = 0; r < 4; ++r) Sp_lds[w][g4 * 4 + r] = tmp_[r];      \
    }                                                                                     \
    asm volatile("s_waitcnt vmcnt(0)" ::: "memory");                                      \
    __syncthreads();                                                                      \
    if (w == 0) {                                                                         \
      if (lane < 16) {                                                                    \
        float sw_ = Sp_lds[0][lane] + Sp_lds[1][lane] + Sp_lds[2][lane] + Sp_lds[3][lane];\
        uint64_t sa_ = wsu + OFF_SPART + (size_t)(((c * 2 + par_) * WPC + j) * MB + lane) * 4; \
        asm volatile("global_store_dword %0, %1, off sc0 sc1\n\ts_waitcnt vmcnt(0)" ::    \
                     "v"(sa_), "v"(sw_) : "memory");                                      \
      }                                                                                   \
      if (lane == 0) {                                                                    \
        uint64_t fa_ = wsu + OFF_FLAGS + (size_t)(c * WPC + j) * 4;                       \
        int fv_ = (TCUR) + 1;                                                             \
        asm volatile("global_store_dword %0, %1, off sc0 sc1" :: "v"(fa_), "v"(fv_)       \
                     : "memory");                                                         \
      }                                                                                   \
    }                                                                                     \
  } while (0)

  // wait until all 16 WGs of the cluster posted flag >= TGT
#define WAIT_FLAGS(TGT)                                                                   \
  do {                                                                                    \
    if (w == 0) {                                                                         \
      const uint64_t fa_ = wsu + OFF_FLAGS + (size_t)(c * WPC + cL) * 4;                  \
      for (;;) {                                                                          \
        int f_;                                                                           \
        asm volatile("global_load_dword %0, %1, off sc0 sc1\n\ts_waitcnt vmcnt(0)"        \
                     : "=v"(f_) : "v"(fa_) : "memory");                                   \
        if (__all(f_ >= (TGT))) break;                                                    \
        __builtin_amdgcn_s_sleep(2);                                                      \
      }                                                                                   \
    }                                                                                     \
    __syncthreads();                                                                      \
  } while (0)

  // load 16 WG-partials for parity PARP, produce s (=S[m=cL] in every lane)
#define SPART_BLOCK(PARP, SVAR)                                                           \
  float SVAR;                                                                             \
  do {                                                                                    \
    const uint64_t sb_ = wsu + OFF_SPART + (size_t)((c * 2 + (PARP)) * WPC) * MB * 4;     \
    float p0_, p1_, p2_, p3_;                                                             \
    uint64_t a0_ = sb_ + (size_t)((g4 + 0) * MB + cL) * 4;                                \
    uint64_t a1_ = sb_ + (size_t)((g4 + 4) * MB + cL) * 4;                                \
    uint64_t a2_ = sb_ + (size_t)((g4 + 8) * MB + cL) * 4;                                \
    uint64_t a3_ = sb_ + (size_t)((g4 + 12) * MB + cL) * 4;                               \
    asm volatile("global_load_dword %0, %4, off sc0 sc1\n\t"                              \
                 "global_load_dword %1, %5, off sc0 sc1\n\t"                              \
                 "global_load_dword %2, %6, off sc0 sc1\n\t"                              \
                 "global_load_dword %3, %7, off sc0 sc1\n\t"                              \
                 "s_waitcnt vmcnt(0)"                                                     \
                 : "=v"(p0_), "=v"(p1_), "=v"(p2_), "=v"(p3_)                             \
                 : "v"(a0_), "v"(a1_), "v"(a2_), "v"(a3_) : "memory");                    \
    SVAR = p0_ + p1_ + p2_ + p3_;                                                         \
    SVAR += __shfl_xor(SVAR, 16);                                                         \
    SVAR += __shfl_xor(SVAR, 32);                                                         \
  } while (0)

  // ---- step 0: u0 = E0 * init ----
#pragma unroll
  for (int r = 0; r < 4; ++r) {
    const int m = g4 * 4 + r;
    const int xm = x_lds[m * TT + 0];
    up0[r] = B_lds[w][cL][xm] * init_lds[w][cL];
    if (two) up1[r] = B_lds[4][cL][xm] * init_lds[4][cL];
  }
  POST_STEP(0);

  float llacc = 0.f;

  for (int t = 1; t < TT; ++t) {
    const int parp = (t - 1) & 1;

    WAIT_FLAGS(t);

    // issue staging loads of g_{t-1} (fragment layout, linear)
    const uint64_t gbp = wsu + OFF_GEX + (size_t)(c * 2 + parp) * GIMG;
    intx4 sgv[8], tl4;
#pragma unroll
    for (int i = 0; i < 8; ++i) {
      uint64_t a = gbp + (size_t)((i * 256 + tid) * 16);
      asm volatile("global_load_dwordx4 %0, %1, off sc0 sc1" : "=v"(sgv[i]) : "v"(a) : "memory");
    }
    const bool has9 = (tid < 64);  // 2112 = 8*256 + 64
    if (has9) {
      uint64_t a = gbp + (size_t)((2048 + tid) * 16);
      asm volatile("global_load_dwordx4 %0, %1, off sc0 sc1" : "=v"(tl4) : "v"(a) : "memory");
    }

    SPART_BLOCK(parp, s);  // also drains the staging loads (vmcnt 0)

    // write staged g into LDS (linear, conflict-free)
#pragma unroll
    for (int i = 0; i < 8; ++i) g_lds[i * 256 + tid] = sgv[i];
    if (has9) g_lds[2048 + tid] = tl4;

    float invS[4];
#pragma unroll
    for (int r = 0; r < 4; ++r) invS[r] = 1.0f / __shfl(s, g4 * 4 + r);

    // forward output for step t-1 (normalized now that S_{t-1} is known)
#pragma unroll
    for (int r = 0; r < 4; ++r) {
      const int m = g4 * 4 + r;
      const size_t ob = ((size_t)(c * MB + m) * TT + (t - 1)) * Q;
      __builtin_nontemporal_store(up0[r] * invS[r], out + ob + tg * 16 + cL);
      if (two && cL < 3)
        __builtin_nontemporal_store(up1[r] * invS[r], out + ob + 1024 + cL);
    }
    __syncthreads();  // g_lds ready

    // matvec: r = g_{t-1} @ A  (per-wave 16x16 tile, K = 1056)
    floatx4 a0v = {0, 0, 0, 0}, a1v = {0, 0, 0, 0}, a64v = {0, 0, 0, 0};
#pragma unroll
    for (int kc = 0; kc < KCH; ++kc) {
      short8 gf = *(const short8*)&g_lds[kc * 64 + lane];
      if (kc & 1) a1v = __builtin_amdgcn_mfma_f32_16x16x32_bf16(gf, af0[kc], a1v, 0, 0, 0);
      else        a0v = __builtin_amdgcn_mfma_f32_16x16x32_bf16(gf, af0[kc], a0v, 0, 0, 0);
    }
    float r1v[4];
    if (jx) {  // extra tile (cols 1024..1039): k-split across the 4 waves
#pragma unroll
      for (int i = 0; i < 9; ++i) {
        if (i < 8 || w == 3) {
          const int kc = w * 8 + i;
          short8 gf = *(const short8*)&g_lds[kc * 64 + lane];
          a64v = __builtin_amdgcn_mfma_f32_16x16x32_bf16(gf, af64[i], a64v, 0, 0, 0);
        }
      }
#pragma unroll
      for (int r = 0; r < 4; ++r) accx_lds[w][lane][r] = a64v[r];
      __syncthreads();
      if (two) {
#pragma unroll
        for (int r = 0; r < 4; ++r)
          r1v[r] = accx_lds[0][lane][r] + accx_lds[1][lane][r] +
                   accx_lds[2][lane][r] + accx_lds[3][lane][r];
      }
    }

    // epilogue: u_t = E_t * r * (1/S_{t-1})
#pragma unroll
    for (int r = 0; r < 4; ++r) {
      const int m = g4 * 4 + r;
      const int xm = x_lds[m * TT + t];
      up0[r] = (a0v[r] + a1v[r]) * B_lds[w][cL][xm] * invS[r];
      if (two) up1[r] = r1v[r] * B_lds[4][cL][xm] * invS[r];
    }

    POST_STEP(t);
    if (j == 0 && w == 0) llacc += logf(s);   // off the critical path
  }

  // ---- final: S_511, output t=511, loglik ----
  WAIT_FLAGS(TT);
  {
    SPART_BLOCK((TT - 1) & 1, s);
    if (j == 0 && w == 0) llacc += logf(s);
    float invS[4];
#pragma unroll
    for (int r = 0; r < 4; ++r) invS[r] = 1.0f / __shfl(s, g4 * 4 + r);
#pragma unroll
    for (int r = 0; r < 4; ++r) {
      const int m = g4 * 4 + r;
      const size_t ob = ((size_t)(c * MB + m) * TT + (TT - 1)) * Q;
      __builtin_nontemporal_store(up0[r] * invS[r], out + ob + tg * 16 + cL);
      if (two && cL < 3)
        __builtin_nontemporal_store(up1[r] * invS[r], out + ob + 1024 + cL);
    }
    if (j == 0 && w == 0 && lane < 16) out[FWDSZ + (size_t)c * MB + lane] = llacc;
  }
}

// ------------------------- launch ------------------------------------------

extern "C" void kernel_launch(void* const* d_in, const int* in_sizes, int n_in,
                              void* d_out, int out_size, void* d_ws, size_t ws_size,
                              hipStream_t stream) {
  const int*   x    = (const int*)d_in[0];
  const float* Alog = (const float*)d_in[1];
  const float* Blog = (const float*)d_in[2];
  const float* ilog = (const float*)d_in[3];
  char*  ws  = (char*)d_ws;
  float* out = (float*)d_out;
  if (ws_size < WS_NEED) return;  // need ~3.3 MB scratch

  hipLaunchKernelGGL(k_zero,   dim3(72),          dim3(256), 0, stream, ws);
  hipLaunchKernelGGL(k_astats, dim3(Q),           dim3(256), 0, stream, Alog, ws);
  hipLaunchKernelGGL(k_bsoft,  dim3(Q),           dim3(64),  0, stream, Blog, ws);
  hipLaunchKernelGGL(k_isoft,  dim3(1),           dim3(256), 0, stream, ilog, ws);
  hipLaunchKernelGGL(k_repack, dim3(NTILE * KCH), dim3(64),  0, stream, Alog, ws);
  hipLaunchKernelGGL(k_main,   dim3(NCL * WPC),   dim3(256), 0, stream, x, ws, out);
}

// Round 7
// 2151.600 us; speedup vs baseline: 1.8555x; 1.0494x over previous
//
#include <hip/hip_runtime.h>
#include <stdint.h>

// ---------------------------------------------------------------------------
// HMM forward: B=256, T=512, Q=1027, ALPHA=26.
// R7 = R6 (2258us) with the serial chain shortened:
//  - POST: g-stores + per-wave Sp f32 slot in ONE burst -> ONE vmcnt(0)
//    (L3 ack only; out-stores issued AFTER the flag) -> per-wave flag.
//    No __syncthreads, no second drain in POST.
//  - Consumer: staged regs ARE the MFMA A-fragments (thread tid holds chunks
//    i*256+tid => wave w holds kc == w (mod 4)). MFMA direct from registers,
//    4-way k-split, cross-wave reduce via accx LDS. g_lds eliminated.
// 16 clusters x 16 WGs (256 thr, 4 waves); wave (j,w) owns tile tg=4j+w;
// WG15 also owns cols 1024..1026 (tile64, k-split over its 4 waves).
// Exchange image in MFMA A-fragment layout (R6-verified):
//   byte(m,k) = kc*1024 + ((k>>3)&3)*256 + m*16 + (k&7)*2, kc=k>>5.
// All cross-WG traffic sc0 sc1 (device scope, placement-independent).
// ---------------------------------------------------------------------------

#define Q     1027
#define TT    512
#define ALPH  26
#define KCH   33              // k-chunks of 32 (K padded to 1056)
#define NTILE 65
#define NCHK  (KCH*64)        // 2112 chunks
#define GIMG  (NCHK*16)       // 33792 B per (cluster,parity) image
#define NCL   16
#define WPC   16
#define MB    16

typedef short  short8  __attribute__((ext_vector_type(8)));
typedef float  floatx4 __attribute__((ext_vector_type(4)));
typedef int    intx4   __attribute__((ext_vector_type(4)));

static constexpr size_t al512(size_t x) { return (x + 511) & ~size_t(511); }
static constexpr size_t OFF_APACK = 0;
static constexpr size_t SZ_APACK  = (size_t)NTILE * KCH * 64 * 16;   // 2,196,480
static constexpr size_t OFF_BSOFT = al512(OFF_APACK + SZ_APACK);
static constexpr size_t SZ_BSOFT  = (size_t)Q * ALPH * 4;
static constexpr size_t OFF_INIT  = al512(OFF_BSOFT + SZ_BSOFT);
static constexpr size_t OFF_AMAX  = al512(OFF_INIT + Q * 4);
static constexpr size_t OFF_AINV  = al512(OFF_AMAX + Q * 4);
static constexpr size_t OFF_GEX   = al512(OFF_AINV + Q * 4);
static constexpr size_t SZ_GEX    = (size_t)NCL * 2 * GIMG;          // 1,081,344
static constexpr size_t OFF_SP    = al512(OFF_GEX + SZ_GEX);         // [c][p][wgi 64][m 16] f32
static constexpr size_t SZ_SP     = (size_t)NCL * 2 * 64 * MB * 4;   // 131,072
static constexpr size_t OFF_FLAGS = al512(OFF_SP + SZ_SP);           // [c][wgi 64] int
static constexpr size_t SZ_FLAGS  = (size_t)NCL * 64 * 4;            // 4,096
static constexpr size_t WS_NEED   = OFF_FLAGS + SZ_FLAGS;            // ~3.38 MB
static constexpr size_t FWDSZ     = (size_t)256 * TT * Q;

__device__ __forceinline__ uint32_t f2bf(float f) {
  uint32_t u = __float_as_uint(f);
  return (u + 0x7fffu + ((u >> 16) & 1u)) >> 16;   // RNE
}

// ------------------------- prep kernels ------------------------------------

__global__ void k_zero(char* __restrict__ ws) {
  const size_t n = (WS_NEED - OFF_GEX) / 16;
  intx4* p = (intx4*)(ws + OFF_GEX);
  for (size_t i = (size_t)blockIdx.x * 256 + threadIdx.x; i < n; i += (size_t)80 * 256)
    p[i] = intx4{0, 0, 0, 0};
}

__global__ void k_astats(const float* __restrict__ A, char* __restrict__ ws) {
  const int r = blockIdx.x, tid = threadIdx.x;
  const float* row = A + (size_t)r * Q;
  __shared__ float red[4], red2[4];
  float mx = -3.0e38f;
  for (int i = tid; i < Q; i += 256) mx = fmaxf(mx, row[i]);
#pragma unroll
  for (int d = 1; d < 64; d <<= 1) mx = fmaxf(mx, __shfl_xor(mx, d));
  if ((tid & 63) == 0) red[tid >> 6] = mx;
  __syncthreads();
  mx = fmaxf(fmaxf(red[0], red[1]), fmaxf(red[2], red[3]));
  float s = 0.f;
  for (int i = tid; i < Q; i += 256) s += expf(row[i] - mx);
#pragma unroll
  for (int d = 1; d < 64; d <<= 1) s += __shfl_xor(s, d);
  if ((tid & 63) == 0) red2[tid >> 6] = s;
  __syncthreads();
  s = red2[0] + red2[1] + red2[2] + red2[3];
  if (tid == 0) {
    *(float*)(ws + OFF_AMAX + (size_t)r * 4) = mx;
    *(float*)(ws + OFF_AINV + (size_t)r * 4) = 1.0f / s;
  }
}

__global__ void k_bsoft(const float* __restrict__ Bl, char* __restrict__ ws) {
  const int r = blockIdx.x, l = threadIdx.x;  // 64 threads
  float v = (l < ALPH) ? Bl[(size_t)r * ALPH + l] : -3.0e38f;
  float mx = v;
#pragma unroll
  for (int d = 1; d < 64; d <<= 1) mx = fmaxf(mx, __shfl_xor(mx, d));
  float e = (l < ALPH) ? expf(v - mx) : 0.f;
  float s = e;
#pragma unroll
  for (int d = 1; d < 64; d <<= 1) s += __shfl_xor(s, d);
  if (l < ALPH) *(float*)(ws + OFF_BSOFT + ((size_t)r * ALPH + l) * 4) = e / s;
}

__global__ void k_isoft(const float* __restrict__ il, char* __restrict__ ws) {
  const int tid = threadIdx.x;
  __shared__ float red[4], red2[4];
  float mx = -3.0e38f;
  for (int i = tid; i < Q; i += 256) mx = fmaxf(mx, il[i]);
#pragma unroll
  for (int d = 1; d < 64; d <<= 1) mx = fmaxf(mx, __shfl_xor(mx, d));
  if ((tid & 63) == 0) red[tid >> 6] = mx;
  __syncthreads();
  mx = fmaxf(fmaxf(red[0], red[1]), fmaxf(red[2], red[3]));
  float s = 0.f;
  for (int i = tid; i < Q; i += 256) s += expf(il[i] - mx);
#pragma unroll
  for (int d = 1; d < 64; d <<= 1) s += __shfl_xor(s, d);
  if ((tid & 63) == 0) red2[tid >> 6] = s;
  __syncthreads();
  s = red2[0] + red2[1] + red2[2] + red2[3];
  const float inv = 1.0f / s;
  for (int i = tid; i < Q; i += 256)
    *(float*)(ws + OFF_INIT + (size_t)i * 4) = expf(il[i] - mx) * inv;
}

// Apack[ntile][kc][lane][e] = A[k = kc*32 + (lane>>4)*8 + e][q = ntile*16 + (lane&15)]
__global__ void k_repack(const float* __restrict__ A, char* __restrict__ ws) {
  const int b = blockIdx.x;
  const int nt = b % NTILE, kc = b / NTILE;
  const int lane = threadIdx.x;
  const int q = nt * 16 + (lane & 15);
  const int kb = kc * 32 + (lane >> 4) * 8;
  union { short8 v; unsigned short u[8]; } pk;
#pragma unroll
  for (int e = 0; e < 8; ++e) {
    const int k = kb + e;
    float val = 0.f;
    if (k < Q && q < Q) {
      const float mxk = *(const float*)(ws + OFF_AMAX + (size_t)k * 4);
      const float ivk = *(const float*)(ws + OFF_AINV + (size_t)k * 4);
      val = expf(A[(size_t)k * Q + q] - mxk) * ivk;
    }
    pk.u[e] = (unsigned short)f2bf(val);
  }
  *(short8*)(ws + OFF_APACK + (((size_t)nt * KCH + kc) * 64 + lane) * 16) = pk.v;
}

// ------------------------- main persistent kernel --------------------------

__global__ __launch_bounds__(256, 1) void k_main(const int* __restrict__ xin,
                                                 char* __restrict__ ws,
                                                 float* __restrict__ out) {
  const int bid = blockIdx.x;
  const int c = bid & 15, j = bid >> 4;
  const int tid = threadIdx.x;
  const int lane = tid & 63, w = tid >> 6;
  const int cL = lane & 15, g4 = lane >> 4;
  const int tg = 4 * j + w;              // 16-col tile 0..63 (== wgi)
  const bool jx = (j == 15), two = (jx && w == 3);
  const uint64_t wsu = (uint64_t)(uintptr_t)ws;

  __shared__ floatx4 accx[4][5][64];     // 20480 B: [wave][tile-slot][lane]
  __shared__ uint8_t x_lds[MB * TT];     // 8192
  __shared__ float   B_lds[5][16][ALPH]; // 8320
  __shared__ float   init_lds[5][16];    // 320
  __shared__ float   SpW[4][16];         // 256

  // ---- stage per-WG constants ----
  for (int idx = tid; idx < MB * TT; idx += 256)
    x_lds[idx] = (uint8_t)xin[(size_t)(c * MB) * TT + idx];
  for (int idx = tid; idx < 5 * 16 * ALPH; idx += 256) {
    const int tl = idx / (16 * ALPH), rem = idx % (16 * ALPH);
    const int cc = rem / ALPH, a = rem % ALPH;
    const int grow = (tl < 4 ? 64 * j + tl * 16 : 1024) + cc;
    B_lds[tl][cc][a] = (grow < Q) ? *(const float*)(ws + OFF_BSOFT + ((size_t)grow * ALPH + a) * 4) : 0.f;
  }
  for (int idx = tid; idx < 5 * 16; idx += 256) {
    const int tl = idx / 16, cc = idx % 16;
    const int grow = (tl < 4 ? 64 * j + tl * 16 : 1024) + cc;
    init_lds[tl][cc] = (grow < Q) ? *(const float*)(ws + OFF_INIT + (size_t)grow * 4) : 0.f;
  }

  // ---- persistent A fragments: af[tt][i] = Apack[4j+tt][kc=4i+w] ----
  short8 af[4][9];
#pragma unroll
  for (int tt = 0; tt < 4; ++tt)
#pragma unroll
    for (int i = 0; i < 9; ++i)
      if (i < 8 || w == 0)
        af[tt][i] = *(const short8*)(ws + OFF_APACK +
                      (((size_t)(4 * j + tt) * KCH + (4 * i + w)) * 64 + lane) * 16);
  short8 afx[9];
  if (jx) {
#pragma unroll
    for (int i = 0; i < 9; ++i)
      if (i < 8 || w == 0)
        afx[i] = *(const short8*)(ws + OFF_APACK +
                      (((size_t)64 * KCH + (4 * i + w)) * 64 + lane) * 16);
  }
  __syncthreads();

  float up0[4], upx[4] = {0.f, 0.f, 0.f, 0.f};
  float uold[4], uxold[4] = {0.f, 0.f, 0.f, 0.f};
  float llacc = 0.f;

  // publish step TCUR: g-stores + per-wave Sp slot, ONE drain, per-wave flag
#define POST_STEP(TCUR)                                                                   \
  do {                                                                                    \
    const int par_ = (TCUR) & 1;                                                          \
    const uint64_t gb_ = wsu + OFF_GEX + (size_t)(c * 2 + par_) * GIMG;                   \
    const uint64_t b0_ = gb_ + (size_t)((tg >> 1) * 1024 + ((tg & 1) * 2 + (cL >> 3)) * 256 \
                         + g4 * 64 + (cL & 7) * 2);                                       \
    float t0_ = up0[0], t1_ = up0[1], t2_ = up0[2], t3_ = up0[3];                         \
    _Pragma("unroll") for (int r = 0; r < 4; ++r) {                                       \
      uint32_t v0_ = f2bf(up0[r]);                                                        \
      asm volatile("global_store_short %0, %1, off sc0 sc1" ::                            \
                   "v"(b0_ + (size_t)(r * 16)), "v"(v0_) : "memory");                     \
    }                                                                                     \
    if (two) {                                                                            \
      const uint64_t bx_ = gb_ + (size_t)(32 * 1024 + (cL >> 3) * 256 + g4 * 64 +         \
                           (cL & 7) * 2);                                                 \
      _Pragma("unroll") for (int r = 0; r < 4; ++r) {                                     \
        uint32_t v1_ = f2bf(upx[r]);                                                      \
        asm volatile("global_store_short %0, %1, off sc0 sc1" ::                          \
                     "v"(bx_ + (size_t)(r * 16)), "v"(v1_) : "memory");                   \
      }                                                                                   \
      t0_ += upx[0]; t1_ += upx[1]; t2_ += upx[2]; t3_ += upx[3];                         \
    }                                                                                     \
    _Pragma("unroll") for (int d = 1; d < 16; d <<= 1) {                                  \
      t0_ += __shfl_xor(t0_, d); t1_ += __shfl_xor(t1_, d);                               \
      t2_ += __shfl_xor(t2_, d); t3_ += __shfl_xor(t3_, d);                               \
    }                                                                                     \
    if (cL == 0) {                                                                        \
      floatx4 sv_; sv_[0] = t0_; sv_[1] = t1_; sv_[2] = t2_; sv_[3] = t3_;                \
      uint64_t sa_ = wsu + OFF_SP + (size_t)(c * 2 + par_) * 4096 +                       \
                     (size_t)(tg * 64 + g4 * 16);                                         \
      asm volatile("global_store_dwordx4 %0, %1, off sc0 sc1" :: "v"(sa_), "v"(sv_)       \
                   : "memory");                                                           \
    }                                                                                     \
    asm volatile("s_waitcnt vmcnt(0)" ::: "memory");                                      \
    __builtin_amdgcn_sched_barrier(0);                                                    \
    if (lane == 0) {                                                                      \
      int fv_ = (TCUR) + 1;                                                               \
      asm volatile("global_store_dword %0, %1, off sc0 sc1" ::                            \
                   "v"(wsu + OFF_FLAGS + (size_t)(c * 64 + tg) * 4), "v"(fv_) : "memory");\
    }                                                                                     \
  } while (0)

  // wave 0 polls all 64 per-wave flags of the cluster, then block sync
#define WAIT_FLAGS(TGT)                                                                   \
  do {                                                                                    \
    if (w == 0) {                                                                         \
      const uint64_t fa_ = wsu + OFF_FLAGS + (size_t)(c * 64 + lane) * 4;                 \
      for (;;) {                                                                          \
        int f_;                                                                           \
        asm volatile("global_load_dword %0, %1, off sc0 sc1\n\ts_waitcnt vmcnt(0)"        \
                     : "=v"(f_) : "v"(fa_) : "memory");                                   \
        if (__all(f_ >= (TGT))) break;                                                    \
        __builtin_amdgcn_s_sleep(2);                                                      \
      }                                                                                   \
    }                                                                                     \
    __syncthreads();                                                                      \
  } while (0)

  // ---- step 0: u0 = E0 * init ----
#pragma unroll
  for (int r = 0; r < 4; ++r) {
    const int m = g4 * 4 + r;
    const int xm = x_lds[m * TT + 0];
    up0[r] = B_lds[w][cL][xm] * init_lds[w][cL];
    uold[r] = up0[r];
    if (two) { upx[r] = B_lds[4][cL][xm] * init_lds[4][cL]; uxold[r] = upx[r]; }
  }
  POST_STEP(0);

  for (int t = 1; t < TT; ++t) {
    const int parp = (t - 1) & 1;
    WAIT_FLAGS(t);

    // stage g_{t-1} fragments (regs ARE the MFMA A-operands) + Sp partials
    const uint64_t gb = wsu + OFF_GEX + (size_t)(c * 2 + parp) * GIMG;
    intx4 sg[9], spi;
#pragma unroll
    for (int i = 0; i < 8; ++i)
      asm volatile("global_load_dwordx4 %0, %1, off sc0 sc1"
                   : "=v"(sg[i]) : "v"(gb + (size_t)((i * 256 + tid) * 16)) : "memory");
    if (w == 0)   // wave-uniform branch: kc=32 chunks
      asm volatile("global_load_dwordx4 %0, %1, off sc0 sc1"
                   : "=v"(sg[8]) : "v"(gb + (size_t)((2048 + lane) * 16)) : "memory");
    asm volatile("global_load_dwordx4 %0, %1, off sc0 sc1"
                 : "=v"(spi)
                 : "v"(wsu + OFF_SP + (size_t)(c * 2 + parp) * 4096 + (size_t)tid * 16)
                 : "memory");
    asm volatile("s_waitcnt vmcnt(1)" ::: "memory");   // all sg arrived; spi in flight
    __builtin_amdgcn_sched_barrier(0);

    // MFMA direct from staged regs: wave w covers kc = 4i+w for its WG's tiles
    floatx4 acc[4] = {{0,0,0,0},{0,0,0,0},{0,0,0,0},{0,0,0,0}};
    floatx4 acx = {0, 0, 0, 0};
#pragma unroll
    for (int i = 0; i < 8; ++i) {
      const short8 gf = __builtin_bit_cast(short8, sg[i]);
#pragma unroll
      for (int tt = 0; tt < 4; ++tt)
        acc[tt] = __builtin_amdgcn_mfma_f32_16x16x32_bf16(gf, af[tt][i], acc[tt], 0, 0, 0);
      if (jx) acx = __builtin_amdgcn_mfma_f32_16x16x32_bf16(gf, afx[i], acx, 0, 0, 0);
    }
    if (w == 0) {  // kc=32 tail
      const short8 gf = __builtin_bit_cast(short8, sg[8]);
#pragma unroll
      for (int tt = 0; tt < 4; ++tt)
        acc[tt] = __builtin_amdgcn_mfma_f32_16x16x32_bf16(gf, af[tt][8], acc[tt], 0, 0, 0);
      if (jx) acx = __builtin_amdgcn_mfma_f32_16x16x32_bf16(gf, afx[8], acx, 0, 0, 0);
    }
    // write k-split partials
#pragma unroll
    for (int tt = 0; tt < 4; ++tt) accx[w][tt][lane] = acc[tt];
    if (jx) accx[w][4][lane] = acx;

    // Sp reduce (per-wave partials over this wave's 16 wgi slots)
    asm volatile("s_waitcnt vmcnt(0)" ::: "memory");
    __builtin_amdgcn_sched_barrier(0);
    floatx4 s4 = __builtin_bit_cast(floatx4, spi);
#pragma unroll
    for (int d = 4; d < 64; d <<= 1) {
#pragma unroll
      for (int e = 0; e < 4; ++e) s4[e] += __shfl_xor(s4[e], d);
    }
    if (lane < 4) *(floatx4*)&SpW[w][lane * 4] = s4;
    __syncthreads();  // accx + SpW ready

    // S_{t-1}, cross-wave k-reduce, epilogue
    float invS[4], ot0[4], ot1[4];
    floatx4 rs = accx[0][w][lane] + accx[1][w][lane] + accx[2][w][lane] + accx[3][w][lane];
    float rx[4];
    if (two) {
      floatx4 q = accx[0][4][lane] + accx[1][4][lane] + accx[2][4][lane] + accx[3][4][lane];
#pragma unroll
      for (int r = 0; r < 4; ++r) rx[r] = q[r];
    }
#pragma unroll
    for (int r = 0; r < 4; ++r) {
      const int m = g4 * 4 + r;
      invS[r] = 1.0f / (SpW[0][m] + SpW[1][m] + SpW[2][m] + SpW[3][m]);
      ot0[r] = uold[r] * invS[r];
      if (two) ot1[r] = uxold[r] * invS[r];
      const int xm = x_lds[m * TT + t];
      up0[r] = rs[r] * B_lds[w][cL][xm] * invS[r];
      uold[r] = up0[r];
      if (two) { upx[r] = rx[r] * B_lds[4][cL][xm] * invS[r]; uxold[r] = upx[r]; }
    }

    POST_STEP(t);

    // forward output for t-1 (after flag post; drains under next staging wait)
#pragma unroll
    for (int r = 0; r < 4; ++r) {
      const int m = g4 * 4 + r;
      const size_t ob = ((size_t)(c * MB + m) * TT + (t - 1)) * Q;
      __builtin_nontemporal_store(ot0[r], out + ob + tg * 16 + cL);
      if (two && cL < 3)
        __builtin_nontemporal_store(ot1[r], out + ob + 1024 + cL);
    }
    if (j == 0 && w == 0 && lane < 16)
      llacc += logf(SpW[0][lane] + SpW[1][lane] + SpW[2][lane] + SpW[3][lane]);
  }

  // ---- final: S_511, fwd_511, loglik ----
  WAIT_FLAGS(TT);
  {
    const int parp = (TT - 1) & 1;
    intx4 spi;
    asm volatile("global_load_dwordx4 %0, %1, off sc0 sc1\n\ts_waitcnt vmcnt(0)"
                 : "=v"(spi)
                 : "v"(wsu + OFF_SP + (size_t)(c * 2 + parp) * 4096 + (size_t)tid * 16)
                 : "memory");
    __builtin_amdgcn_sched_barrier(0);
    floatx4 s4 = __builtin_bit_cast(floatx4, spi);
#pragma unroll
    for (int d = 4; d < 64; d <<= 1) {
#pragma unroll
      for (int e = 0; e < 4; ++e) s4[e] += __shfl_xor(s4[e], d);
    }
    if (lane < 4) *(floatx4*)&SpW[w][lane * 4] = s4;
    __syncthreads();
    float invS[4];
#pragma unroll
    for (int r = 0; r < 4; ++r) {
      const int m = g4 * 4 + r;
      invS[r] = 1.0f / (SpW[0][m] + SpW[1][m] + SpW[2][m] + SpW[3][m]);
    }
#pragma unroll
    for (int r = 0; r < 4; ++r) {
      const int m = g4 * 4 + r;
      const size_t ob = ((size_t)(c * MB + m) * TT + (TT - 1)) * Q;
      __builtin_nontemporal_store(up0[r] * invS[r], out + ob + tg * 16 + cL);
      if (two && cL < 3)
        __builtin_nontemporal_store(upx[r] * invS[r], out + ob + 1024 + cL);
    }
    if (j == 0 && w == 0 && lane < 16) {
      llacc += logf(SpW[0][lane] + SpW[1][lane] + SpW[2][lane] + SpW[3][lane]);
      out[FWDSZ + (size_t)c * MB + lane] = llacc;
    }
  }
}

// ------------------------- launch ------------------------------------------

extern "C" void kernel_launch(void* const* d_in, const int* in_sizes, int n_in,
                              void* d_out, int out_size, void* d_ws, size_t ws_size,
                              hipStream_t stream) {
  const int*   x    = (const int*)d_in[0];
  const float* Alog = (const float*)d_in[1];
  const float* Blog = (const float*)d_in[2];
  const float* ilog = (const float*)d_in[3];
  char*  ws  = (char*)d_ws;
  float* out = (float*)d_out;
  if (ws_size < WS_NEED) return;  // need ~3.4 MB scratch

  hipLaunchKernelGGL(k_zero,   dim3(80),          dim3(256), 0, stream, ws);
  hipLaunchKernelGGL(k_astats, dim3(Q),           dim3(256), 0, stream, Alog, ws);
  hipLaunchKernelGGL(k_bsoft,  dim3(Q),           dim3(64),  0, stream, Blog, ws);
  hipLaunchKernelGGL(k_isoft,  dim3(1),           dim3(256), 0, stream, ilog, ws);
  hipLaunchKernelGGL(k_repack, dim3(NTILE * KCH), dim3(64),  0, stream, Alog, ws);
  hipLaunchKernelGGL(k_main,   dim3(NCL * WPC),   dim3(256), 0, stream, x, ws, out);
}